// Round 1
// baseline (5695.265 us; speedup 1.0000x reference)
//
#include <hip/hip_runtime.h>

// ============================================================================
// StateSequencePredictor  (B=16384, EMBED=512, STATE=128, HIDDEN=256, T=32)
//
// Design:
//  * Rows are independent over the whole horizon -> persistent kernel:
//    256 blocks x 512 threads (8 waves); each block owns 64 rows and runs all
//    32 steps with h0/h1 resident in LDS (fp32, 2 x 64KB, XOR-swizzled).
//  * No fp32 MFMA on CDNA4 -> emulate fp32 GEMM with 3-term split bf16:
//    x@W ~= x_hi@W_hi + x_lo@W_hi + x_hi@W_lo   (~17-bit mantissa).
//    Weights pre-split to bf16 hi/lo in d_ws by a prep kernel (every call).
//  * Wave w owns gate columns [32w,32w+32) (so r/z/n triples stay wave-local),
//    processed in 2 passes of 16 cols to bound accumulator VGPRs (64).
//  * MFMA 16x16x32 bf16. k-permutation inside fragments cancels between A and
//    B as long as both use the same map; C layout col=lane&15,row=(lane>>4)*4+j
//    (learn_hip m89-verified).
//  * next_state round-trips through d_ws (global, block-private rows, L2-hot);
//    t==0 reads initial_state directly.
// ============================================================================

#define BTOT    16384
#define EMBED   512
#define STATE   128
#define HIDDEN  256
#define HORIZON 32

#define ROWS_PER_BLK 64
#define THREADS      512

typedef __attribute__((ext_vector_type(4))) float f32x4;
typedef __attribute__((ext_vector_type(8))) short s16x8;

#define N_Wp    (HIDDEN*EMBED)
#define N_Wih0  (3*HIDDEN*STATE)
#define N_Whh0  (3*HIDDEN*HIDDEN)
#define N_Wih1  (3*HIDDEN*HIDDEN)
#define N_Whh1  (3*HIDDEN*HIDDEN)
#define N_Wo    (STATE*HIDDEN)
#define OFF_Wp   0
#define OFF_Wih0 (OFF_Wp   + N_Wp)
#define OFF_Whh0 (OFF_Wih0 + N_Wih0)
#define OFF_Wih1 (OFF_Whh0 + N_Whh0)
#define OFF_Whh1 (OFF_Wih1 + N_Wih1)
#define OFF_Wo   (OFF_Whh1 + N_Whh1)
#define N_WTOT   (OFF_Wo   + N_Wo)      // 851968 elements

// ---------------- bf16 helpers (RNE) ----------------
__device__ __forceinline__ short f2bf(float f) {
    unsigned u = __float_as_uint(f);
    u += 0x7FFFu + ((u >> 16) & 1u);
    return (short)(u >> 16);
}
__device__ __forceinline__ float bf2f(short h) {
    return __uint_as_float(((unsigned)(unsigned short)h) << 16);
}
__device__ __forceinline__ void split8(const f32x4 a, const f32x4 b, s16x8 &hi, s16x8 &lo) {
#pragma unroll
    for (int i = 0; i < 4; i++) {
        short h = f2bf(a[i]); hi[i] = h; lo[i] = f2bf(a[i] - bf2f(h));
    }
#pragma unroll
    for (int i = 0; i < 4; i++) {
        short h = f2bf(b[i]); hi[4+i] = h; lo[4+i] = f2bf(b[i] - bf2f(h));
    }
}

// XOR-swizzled LDS index (16B granule; stride = floats/row, multiple of 32).
// Breaks the 16-lanes-same-column bank conflict on ds_read_b128 (T2 / G4).
__device__ __forceinline__ int swz(int row, int col, int stride) {
    return row * stride + ((((col >> 2) ^ (row & 7)) << 2) | (col & 3));
}

// A-fragment (8 consecutive k, fp32 in LDS) -> split bf16 hi/lo
template<int STRIDE>
__device__ __forceinline__ void lds_frag(const float* H, int row, int k0, s16x8 &hi, s16x8 &lo) {
    int base = row * STRIDE;
    int s0 = (((k0 >> 2)    ) ^ (row & 7)) << 2;
    int s1 = (((k0 >> 2) + 1) ^ (row & 7)) << 2;
    f32x4 a = *(const f32x4*)(H + base + s0);
    f32x4 b = *(const f32x4*)(H + base + s1);
    split8(a, b, hi, lo);
}
// A-fragment from global fp32 (state S, row-major stride=STATE)
__device__ __forceinline__ void glob_frag(const float* __restrict__ S, int row, int k0,
                                          s16x8 &hi, s16x8 &lo) {
    f32x4 a = *(const f32x4*)(S + (size_t)row * STATE + k0);
    f32x4 b = *(const f32x4*)(S + (size_t)row * STATE + k0 + 4);
    split8(a, b, hi, lo);
}

#define MFMA(A, B, C) __builtin_amdgcn_mfma_f32_16x16x32_bf16(A, B, C, 0, 0, 0)

// One gate-category block: load W hi/lo fragment, 3-term split MFMA into 4 M-tiles.
// (term-outer / mt-inner ordering -> 4 independent accumulation chains)
template<int KW>
__device__ __forceinline__ void catblock(f32x4 (&acc)[4],
                                         const s16x8 (&ahi)[4], const s16x8 (&alo)[4],
                                         const short* __restrict__ WHi,
                                         const short* __restrict__ WLo,
                                         int wr, int k0) {
    s16x8 bhi = *(const s16x8*)(WHi + wr * KW + k0);
    s16x8 blo = *(const s16x8*)(WLo + wr * KW + k0);
#pragma unroll
    for (int mt = 0; mt < 4; mt++) acc[mt] = MFMA(ahi[mt], bhi, acc[mt]);
#pragma unroll
    for (int mt = 0; mt < 4; mt++) acc[mt] = MFMA(alo[mt], bhi, acc[mt]);
#pragma unroll
    for (int mt = 0; mt < 4; mt++) acc[mt] = MFMA(ahi[mt], blo, acc[mt]);
}

__device__ __forceinline__ float sigf(float x)  { return 1.0f / (1.0f + __expf(-x)); }
__device__ __forceinline__ float tanhf_(float x){ return 1.0f - 2.0f / (__expf(2.0f * x) + 1.0f); }

// ---------------- one GRU layer (both passes), result in hnew[2][4][4] ----------------
// KI: input-dim; AGLOB: A_i from global (state) vs LDS (h0)
template<int KI, bool AGLOB>
__device__ __forceinline__ void gru_layer(
    const float* __restrict__ Ai,     // input x: global rows (abs) or LDS [64][KI] swizzled
    const float* __restrict__ Hlds,   // old hidden, LDS [64][256] swizzled
    const short* __restrict__ WihHi, const short* __restrict__ WihLo,
    const short* __restrict__ WhhHi, const short* __restrict__ WhhLo,
    const float* __restrict__ bih,   const float* __restrict__ bhh,
    int rowbase, int wave, int lr, int lg,
    float hnew[2][4][4])
{
#pragma unroll
    for (int p = 0; p < 2; p++) {
        f32x4 aR[4], aZ[4], aI[4], aH[4];
        {
            f32x4 zz = {0.f, 0.f, 0.f, 0.f};
#pragma unroll
            for (int mt = 0; mt < 4; mt++) { aR[mt]=zz; aZ[mt]=zz; aI[mt]=zz; aH[mt]=zz; }
        }
        const int hcol = wave * 32 + p * 16 + lr;   // this lane's gate column
        // ---- gi = x @ Wih^T  (r,z into shared acc with gh; inn separate) ----
#pragma unroll 2
        for (int kc = 0; kc < KI / 32; kc++) {
            const int k0 = kc * 32 + lg * 8;
            s16x8 ahi[4], alo[4];
#pragma unroll
            for (int mt = 0; mt < 4; mt++) {
                if constexpr (AGLOB) glob_frag(Ai, rowbase + mt * 16 + lr, k0, ahi[mt], alo[mt]);
                else                 lds_frag<KI>(Ai, mt * 16 + lr, k0, ahi[mt], alo[mt]);
            }
            catblock<KI>(aR, ahi, alo, WihHi, WihLo, 0 * HIDDEN + hcol, k0);
            catblock<KI>(aZ, ahi, alo, WihHi, WihLo, 1 * HIDDEN + hcol, k0);
            catblock<KI>(aI, ahi, alo, WihHi, WihLo, 2 * HIDDEN + hcol, k0);
        }
        // ---- gh = h_old @ Whh^T  (K = 256) ----
#pragma unroll 2
        for (int kc = 0; kc < HIDDEN / 32; kc++) {
            const int k0 = kc * 32 + lg * 8;
            s16x8 ahi[4], alo[4];
#pragma unroll
            for (int mt = 0; mt < 4; mt++)
                lds_frag<HIDDEN>(Hlds, mt * 16 + lr, k0, ahi[mt], alo[mt]);
            catblock<HIDDEN>(aR, ahi, alo, WhhHi, WhhLo, 0 * HIDDEN + hcol, k0);
            catblock<HIDDEN>(aZ, ahi, alo, WhhHi, WhhLo, 1 * HIDDEN + hcol, k0);
            catblock<HIDDEN>(aH, ahi, alo, WhhHi, WhhLo, 2 * HIDDEN + hcol, k0);
        }
        // ---- elementwise gates (fp32) ----
        const float b_r = bih[hcol]            + bhh[hcol];
        const float b_z = bih[HIDDEN + hcol]   + bhh[HIDDEN + hcol];
        const float b_i = bih[2 * HIDDEN + hcol];
        const float b_h = bhh[2 * HIDDEN + hcol];
#pragma unroll
        for (int mt = 0; mt < 4; mt++)
#pragma unroll
            for (int j = 0; j < 4; j++) {
                int row  = mt * 16 + lg * 4 + j;
                float r  = sigf(aR[mt][j] + b_r);
                float z  = sigf(aZ[mt][j] + b_z);
                float n  = tanhf_(aI[mt][j] + b_i + r * (aH[mt][j] + b_h));
                float ho = Hlds[swz(row, hcol, HIDDEN)];
                hnew[p][mt][j] = (1.0f - z) * n + z * ho;
            }
    }
}

__device__ __forceinline__ void write_h(float* Hlds, const float hnew[2][4][4],
                                        int wave, int lr, int lg) {
#pragma unroll
    for (int p = 0; p < 2; p++) {
        int col = wave * 32 + p * 16 + lr;
#pragma unroll
        for (int mt = 0; mt < 4; mt++)
#pragma unroll
            for (int j = 0; j < 4; j++)
                Hlds[swz(mt * 16 + lg * 4 + j, col, HIDDEN)] = hnew[p][mt][j];
    }
}

// ---------------- weight split prep (runs every call; ~0.85M elems) ----------------
__global__ void prep_split(const float* __restrict__ Wp,   const float* __restrict__ Wih0,
                           const float* __restrict__ Whh0, const float* __restrict__ Wih1,
                           const float* __restrict__ Whh1, const float* __restrict__ Wo,
                           short* __restrict__ hi, short* __restrict__ lo) {
    int i = blockIdx.x * 256 + threadIdx.x;
    if (i >= N_WTOT) return;
    float w;
    if      (i < OFF_Wih0) w = Wp  [i - OFF_Wp];
    else if (i < OFF_Whh0) w = Wih0[i - OFF_Wih0];
    else if (i < OFF_Wih1) w = Whh0[i - OFF_Whh0];
    else if (i < OFF_Whh1) w = Wih1[i - OFF_Wih1];
    else if (i < OFF_Wo)   w = Whh1[i - OFF_Whh1];
    else                   w = Wo  [i - OFF_Wo];
    short h = f2bf(w);
    hi[i] = h;
    lo[i] = f2bf(w - bf2f(h));
}

// ---------------- persistent GRU kernel ----------------
__global__ __launch_bounds__(THREADS, 2)
void gru_main(const float* __restrict__ emb,  const float* __restrict__ init_state,
              const float* __restrict__ bp,
              const float* __restrict__ bih0, const float* __restrict__ bhh0,
              const float* __restrict__ bih1, const float* __restrict__ bhh1,
              const float* __restrict__ bo,
              const short* __restrict__ Whi,  const short* __restrict__ Wlo,
              float* __restrict__ wsS, float* __restrict__ out) {
    __shared__ float smem[ROWS_PER_BLK * EMBED];        // 128 KiB
    float* H0 = smem;                                   // [64][256] swizzled fp32
    float* H1 = smem + ROWS_PER_BLK * HIDDEN;

    const int tid  = threadIdx.x;
    const int wave = tid >> 6, lane = tid & 63;
    const int lr = lane & 15, lg = lane >> 4;
    const int rowbase = blockIdx.x * ROWS_PER_BLK;

    const short *WpHi   = Whi + OFF_Wp,   *WpLo   = Wlo + OFF_Wp;
    const short *Wih0Hi = Whi + OFF_Wih0, *Wih0Lo = Wlo + OFF_Wih0;
    const short *Whh0Hi = Whi + OFF_Whh0, *Whh0Lo = Wlo + OFF_Whh0;
    const short *Wih1Hi = Whi + OFF_Wih1, *Wih1Lo = Wlo + OFF_Wih1;
    const short *Whh1Hi = Whi + OFF_Whh1, *Whh1Lo = Wlo + OFF_Whh1;
    const short *WoHi   = Whi + OFF_Wo,   *WoLo   = Wlo + OFF_Wo;

    // ===== prologue: h_init = emb @ Wp^T + bp  (emb staged over all 128KB LDS) =====
    for (int idx = tid; idx < ROWS_PER_BLK * EMBED; idx += THREADS) {
        int r = idx >> 9, c = idx & (EMBED - 1);
        smem[swz(r, c, EMBED)] = emb[(size_t)(rowbase + r) * EMBED + c];
    }
    __syncthreads();
    f32x4 hacc[2][4];
    {
        f32x4 zz = {0.f, 0.f, 0.f, 0.f};
#pragma unroll
        for (int nt = 0; nt < 2; nt++)
#pragma unroll
            for (int mt = 0; mt < 4; mt++) hacc[nt][mt] = zz;
    }
#pragma unroll 2
    for (int kc = 0; kc < EMBED / 32; kc++) {
        const int k0 = kc * 32 + lg * 8;
        s16x8 ahi[4], alo[4];
#pragma unroll
        for (int mt = 0; mt < 4; mt++)
            lds_frag<EMBED>(smem, mt * 16 + lr, k0, ahi[mt], alo[mt]);
#pragma unroll
        for (int nt = 0; nt < 2; nt++)
            catblock<EMBED>(hacc[nt], ahi, alo, WpHi, WpLo, wave * 32 + nt * 16 + lr, k0);
    }
    __syncthreads();   // emb reads done before overwrite with H0/H1
#pragma unroll
    for (int nt = 0; nt < 2; nt++)
#pragma unroll
        for (int mt = 0; mt < 4; mt++)
#pragma unroll
            for (int j = 0; j < 4; j++) {
                int row = mt * 16 + lg * 4 + j;
                int col = wave * 32 + nt * 16 + lr;
                float v = hacc[nt][mt][j] + bp[col];
                H0[swz(row, col, HIDDEN)] = v;
                H1[swz(row, col, HIDDEN)] = v;
            }
    __syncthreads();

    // ===== 32 recurrent steps, fully block-local =====
    for (int t = 0; t < HORIZON; t++) {
        const float* Srd = (t == 0) ? init_state : wsS;

        float hn0[2][4][4];
        gru_layer<STATE, true>(Srd, H0, Wih0Hi, Wih0Lo, Whh0Hi, Whh0Lo,
                               bih0, bhh0, rowbase, wave, lr, lg, hn0);
        __syncthreads();                 // all gh0 reads of old H0 done
        write_h(H0, hn0, wave, lr, lg);
        __syncthreads();                 // new H0 visible

        float hn1[2][4][4];
        gru_layer<HIDDEN, false>(H0, H1, Wih1Hi, Wih1Lo, Whh1Hi, Whh1Lo,
                                 bih1, bhh1, rowbase, wave, lr, lg, hn1);
        __syncthreads();                 // all gh1 reads of old H1 done
        write_h(H1, hn1, wave, lr, lg);
        __syncthreads();                 // new H1 visible

        // ---- next_state = h1 @ Wo^T + bo ; emit to out[:,t,:] and wsS ----
        f32x4 o[4];
        {
            f32x4 zz = {0.f, 0.f, 0.f, 0.f};
#pragma unroll
            for (int mt = 0; mt < 4; mt++) o[mt] = zz;
        }
#pragma unroll 2
        for (int kc = 0; kc < HIDDEN / 32; kc++) {
            const int k0 = kc * 32 + lg * 8;
            s16x8 ahi[4], alo[4];
#pragma unroll
            for (int mt = 0; mt < 4; mt++)
                lds_frag<HIDDEN>(H1, mt * 16 + lr, k0, ahi[mt], alo[mt]);
            catblock<HIDDEN>(o, ahi, alo, WoHi, WoLo, wave * 16 + lr, k0);
        }
        const int scol = wave * 16 + lr;     // 8 waves x 16 = 128 state cols
        const float bov = bo[scol];
#pragma unroll
        for (int mt = 0; mt < 4; mt++)
#pragma unroll
            for (int j = 0; j < 4; j++) {
                int row   = mt * 16 + lg * 4 + j;
                size_t gr = (size_t)(rowbase + row);
                float v   = o[mt][j] + bov;
                out[gr * (size_t)(HORIZON * STATE) + (size_t)t * STATE + scol] = v;
                wsS[gr * STATE + scol] = v;
            }
        __threadfence_block();   // S writes visible to this block's next-step reads
        __syncthreads();
    }
}

extern "C" void kernel_launch(void* const* d_in, const int* in_sizes, int n_in,
                              void* d_out, int out_size, void* d_ws, size_t ws_size,
                              hipStream_t stream) {
    (void)in_sizes; (void)n_in; (void)out_size; (void)ws_size;
    const float* emb  = (const float*)d_in[0];
    const float* st0  = (const float*)d_in[1];
    const float* Wp   = (const float*)d_in[2];
    const float* bp   = (const float*)d_in[3];
    const float* Wih0 = (const float*)d_in[4];
    const float* Whh0 = (const float*)d_in[5];
    const float* bih0 = (const float*)d_in[6];
    const float* bhh0 = (const float*)d_in[7];
    const float* Wih1 = (const float*)d_in[8];
    const float* Whh1 = (const float*)d_in[9];
    const float* bih1 = (const float*)d_in[10];
    const float* bhh1 = (const float*)d_in[11];
    const float* Wo   = (const float*)d_in[12];
    const float* bo   = (const float*)d_in[13];
    float* out = (float*)d_out;

    // d_ws layout: [ S fp32 16384x128 (8 MiB) | W_hi bf16 (1.66 MiB) | W_lo bf16 ]
    float* wsS = (float*)d_ws;
    short* whi = (short*)((char*)d_ws + (size_t)BTOT * STATE * sizeof(float));
    short* wlo = whi + N_WTOT;

    prep_split<<<(N_WTOT + 255) / 256, 256, 0, stream>>>(Wp, Wih0, Whh0, Wih1, Whh1, Wo, whi, wlo);
    gru_main<<<BTOT / ROWS_PER_BLK, THREADS, 0, stream>>>(
        emb, st0, bp, bih0, bhh0, bih1, bhh1, bo, whi, wlo, wsS, out);
}

// Round 2
// 5611.245 us; speedup vs baseline: 1.0150x; 1.0150x over previous
//
#include <hip/hip_runtime.h>

// ============================================================================
// StateSequencePredictor  (B=16384, EMBED=512, STATE=128, HIDDEN=256, T=32)
//
// R2: hidden states h0/h1 and recurrent state S are stored ALREADY SPLIT as
// bf16 hi/lo planes (same byte footprint as fp32). Inner loop = ds_read_b128
// (hi,lo) + MFMA only; the fp32->bf16x2 split runs once per element at write
// time. This removes the ~2.8:1 VALU:MFMA imbalance seen in R1
// (MfmaUtil 17% / VALUBusy 41%).
//
//  * 256 blocks x 512 threads (8 waves); block owns 64 rows, all 32 steps.
//  * LDS 128KB: H0hi|H0lo|H1hi|H1lo, each [64][256] bf16, 16B-granule
//    XOR-swizzle (granule ^= row&7) for conflict-free ds_read_b128.
//  * 3-term split fp32 emulation: x@W ~= xh@Wh + xl@Wh + xh@Wl.
//  * S (16384x128) lives in d_ws as bf16 hi/lo planes; written by the Wo
//    stage, read by layer-0 gi; prep kernel seeds it from initial_state.
// ============================================================================

#define BTOT    16384
#define EMBED   512
#define STATE   128
#define HIDDEN  256
#define HORIZON 32

#define ROWS_PER_BLK 64
#define THREADS      512

typedef __attribute__((ext_vector_type(4))) float f32x4;
typedef __attribute__((ext_vector_type(8))) short s16x8;

#define N_Wp    (HIDDEN*EMBED)
#define N_Wih0  (3*HIDDEN*STATE)
#define N_Whh0  (3*HIDDEN*HIDDEN)
#define N_Wih1  (3*HIDDEN*HIDDEN)
#define N_Whh1  (3*HIDDEN*HIDDEN)
#define N_Wo    (STATE*HIDDEN)
#define OFF_Wp   0
#define OFF_Wih0 (OFF_Wp   + N_Wp)
#define OFF_Whh0 (OFF_Wih0 + N_Wih0)
#define OFF_Wih1 (OFF_Whh0 + N_Whh0)
#define OFF_Whh1 (OFF_Wih1 + N_Wih1)
#define OFF_Wo   (OFF_Whh1 + N_Whh1)
#define N_WTOT   (OFF_Wo   + N_Wo)      // 851968 elements

// ---------------- bf16 helpers (RNE) ----------------
__device__ __forceinline__ short f2bf(float f) {
    unsigned u = __float_as_uint(f);
    u += 0x7FFFu + ((u >> 16) & 1u);
    return (short)(u >> 16);
}
__device__ __forceinline__ float bf2f(short h) {
    return __uint_as_float(((unsigned)(unsigned short)h) << 16);
}
__device__ __forceinline__ void split8(const f32x4 a, const f32x4 b, s16x8 &hi, s16x8 &lo) {
#pragma unroll
    for (int i = 0; i < 4; i++) {
        short h = f2bf(a[i]); hi[i] = h; lo[i] = f2bf(a[i] - bf2f(h));
    }
#pragma unroll
    for (int i = 0; i < 4; i++) {
        short h = f2bf(b[i]); hi[4+i] = h; lo[4+i] = f2bf(b[i] - bf2f(h));
    }
}

// ---- LDS short-plane addressing: [64][256] bf16, 16B-granule XOR swizzle ----
__device__ __forceinline__ int sidx(int row, int col) {
    return row * 256 + ((((col >> 3) ^ (row & 7)) << 3) | (col & 7));
}
__device__ __forceinline__ int sfrag(int row, int k0) {   // k0 multiple of 8
    return row * 256 + (((k0 >> 3) ^ (row & 7)) << 3);
}

// ---- fp32 LDS addressing for the prologue emb tile [64][512] ----
__device__ __forceinline__ int fswz(int row, int col) {
    return row * EMBED + ((((col >> 2) ^ (row & 7)) << 2) | (col & 3));
}
__device__ __forceinline__ void lds_frag_f32(const float* H, int row, int k0,
                                             s16x8 &hi, s16x8 &lo) {
    int base = row * EMBED;
    int s0 = (((k0 >> 2)    ) ^ (row & 7)) << 2;
    int s1 = (((k0 >> 2) + 1) ^ (row & 7)) << 2;
    f32x4 a = *(const f32x4*)(H + base + s0);
    f32x4 b = *(const f32x4*)(H + base + s1);
    split8(a, b, hi, lo);
}

#define MFMA(A, B, C) __builtin_amdgcn_mfma_f32_16x16x32_bf16(A, B, C, 0, 0, 0)

// 3-term split MFMA block for one gate-category (12 MFMAs, 4 indep M chains)
template<int KW>
__device__ __forceinline__ void catblock(f32x4 (&acc)[4],
                                         const s16x8 (&ahi)[4], const s16x8 (&alo)[4],
                                         const short* __restrict__ WHi,
                                         const short* __restrict__ WLo,
                                         int wr, int k0) {
    s16x8 bhi = *(const s16x8*)(WHi + wr * KW + k0);
    s16x8 blo = *(const s16x8*)(WLo + wr * KW + k0);
#pragma unroll
    for (int mt = 0; mt < 4; mt++) acc[mt] = MFMA(ahi[mt], bhi, acc[mt]);
#pragma unroll
    for (int mt = 0; mt < 4; mt++) acc[mt] = MFMA(alo[mt], bhi, acc[mt]);
#pragma unroll
    for (int mt = 0; mt < 4; mt++) acc[mt] = MFMA(ahi[mt], blo, acc[mt]);
}

__device__ __forceinline__ float sigf(float x)  { return 1.0f / (1.0f + __expf(-x)); }
__device__ __forceinline__ float tanhf_(float x){ return 1.0f - 2.0f / (__expf(2.0f * x) + 1.0f); }

// ---------------- one GRU layer (2 passes of 16 gate cols per wave) ----------------
// KI: input dim.  AGLOB: input x from global split planes (absolute rows,
// row-major stride KI) vs LDS split planes (local rows, swizzled stride 256).
template<int KI, bool AGLOB>
__device__ __forceinline__ void gru_layer(
    const short* __restrict__ AiHi, const short* __restrict__ AiLo,
    const short* __restrict__ HHi,  const short* __restrict__ HLo,
    const short* __restrict__ WihHi, const short* __restrict__ WihLo,
    const short* __restrict__ WhhHi, const short* __restrict__ WhhLo,
    const float br[2], const float bz[2], const float bi[2], const float bh[2],
    int rowbase, int wave, int lr, int lg,
    float hnew[2][4][4])
{
#pragma unroll
    for (int p = 0; p < 2; p++) {
        f32x4 aR[4], aZ[4], aI[4], aH[4];
        {
            f32x4 zz = {0.f, 0.f, 0.f, 0.f};
#pragma unroll
            for (int mt = 0; mt < 4; mt++) { aR[mt]=zz; aZ[mt]=zz; aI[mt]=zz; aH[mt]=zz; }
        }
        const int hcol = wave * 32 + p * 16 + lr;
        // ---- gi = x @ Wih^T ----
#pragma unroll 2
        for (int kc = 0; kc < KI / 32; kc++) {
            const int k0 = kc * 32 + lg * 8;
            s16x8 ahi[4], alo[4];
#pragma unroll
            for (int mt = 0; mt < 4; mt++) {
                if constexpr (AGLOB) {
                    size_t base = (size_t)(rowbase + mt * 16 + lr) * KI + k0;
                    ahi[mt] = *(const s16x8*)(AiHi + base);
                    alo[mt] = *(const s16x8*)(AiLo + base);
                } else {
                    int off = sfrag(mt * 16 + lr, k0);
                    ahi[mt] = *(const s16x8*)(AiHi + off);
                    alo[mt] = *(const s16x8*)(AiLo + off);
                }
            }
            catblock<KI>(aR, ahi, alo, WihHi, WihLo, 0 * HIDDEN + hcol, k0);
            catblock<KI>(aZ, ahi, alo, WihHi, WihLo, 1 * HIDDEN + hcol, k0);
            catblock<KI>(aI, ahi, alo, WihHi, WihLo, 2 * HIDDEN + hcol, k0);
        }
        // ---- gh = h_old @ Whh^T  (K = 256, from LDS split planes) ----
#pragma unroll 2
        for (int kc = 0; kc < HIDDEN / 32; kc++) {
            const int k0 = kc * 32 + lg * 8;
            s16x8 ahi[4], alo[4];
#pragma unroll
            for (int mt = 0; mt < 4; mt++) {
                int off = sfrag(mt * 16 + lr, k0);
                ahi[mt] = *(const s16x8*)(HHi + off);
                alo[mt] = *(const s16x8*)(HLo + off);
            }
            catblock<HIDDEN>(aR, ahi, alo, WhhHi, WhhLo, 0 * HIDDEN + hcol, k0);
            catblock<HIDDEN>(aZ, ahi, alo, WhhHi, WhhLo, 1 * HIDDEN + hcol, k0);
            catblock<HIDDEN>(aH, ahi, alo, WhhHi, WhhLo, 2 * HIDDEN + hcol, k0);
        }
        // ---- elementwise gates (fp32) ----
#pragma unroll
        for (int mt = 0; mt < 4; mt++)
#pragma unroll
            for (int j = 0; j < 4; j++) {
                int row  = mt * 16 + lg * 4 + j;
                float r  = sigf(aR[mt][j] + br[p]);
                float z  = sigf(aZ[mt][j] + bz[p]);
                float n  = tanhf_(aI[mt][j] + bi[p] + r * (aH[mt][j] + bh[p]));
                float ho = bf2f(HHi[sidx(row, hcol)]) + bf2f(HLo[sidx(row, hcol)]);
                hnew[p][mt][j] = (1.0f - z) * n + z * ho;
            }
    }
}

__device__ __forceinline__ void write_h(short* HHi, short* HLo, const float hnew[2][4][4],
                                        int wave, int lr, int lg) {
#pragma unroll
    for (int p = 0; p < 2; p++) {
        int col = wave * 32 + p * 16 + lr;
#pragma unroll
        for (int mt = 0; mt < 4; mt++)
#pragma unroll
            for (int j = 0; j < 4; j++) {
                int row = mt * 16 + lg * 4 + j;
                float v = hnew[p][mt][j];
                short hi = f2bf(v);
                short lo = f2bf(v - bf2f(hi));
                HHi[sidx(row, col)] = hi;
                HLo[sidx(row, col)] = lo;
            }
    }
}

// ---------------- prep: split weights ----------------
__global__ void prep_split(const float* __restrict__ Wp,   const float* __restrict__ Wih0,
                           const float* __restrict__ Whh0, const float* __restrict__ Wih1,
                           const float* __restrict__ Whh1, const float* __restrict__ Wo,
                           short* __restrict__ hi, short* __restrict__ lo) {
    int i = blockIdx.x * 256 + threadIdx.x;
    if (i >= N_WTOT) return;
    float w;
    if      (i < OFF_Wih0) w = Wp  [i - OFF_Wp];
    else if (i < OFF_Whh0) w = Wih0[i - OFF_Wih0];
    else if (i < OFF_Wih1) w = Whh0[i - OFF_Whh0];
    else if (i < OFF_Whh1) w = Wih1[i - OFF_Wih1];
    else if (i < OFF_Wo)   w = Whh1[i - OFF_Whh1];
    else                   w = Wo  [i - OFF_Wo];
    short h = f2bf(w);
    hi[i] = h;
    lo[i] = f2bf(w - bf2f(h));
}

// ---------------- prep: split initial_state into S planes ----------------
__global__ void prep_state(const float* __restrict__ s0,
                           short* __restrict__ shi, short* __restrict__ slo) {
    int i = blockIdx.x * 256 + threadIdx.x;
    if (i >= BTOT * STATE) return;
    float w = s0[i];
    short h = f2bf(w);
    shi[i] = h;
    slo[i] = f2bf(w - bf2f(h));
}

// ---------------- persistent GRU kernel ----------------
__global__ __launch_bounds__(THREADS, 2)
void gru_main(const float* __restrict__ emb,
              const float* __restrict__ bp,
              const float* __restrict__ bih0, const float* __restrict__ bhh0,
              const float* __restrict__ bih1, const float* __restrict__ bhh1,
              const float* __restrict__ bo,
              const short* __restrict__ Whi,  const short* __restrict__ Wlo,
              short* __restrict__ Shi, short* __restrict__ Slo,
              float* __restrict__ out) {
    __shared__ short sH[4 * ROWS_PER_BLK * HIDDEN];     // 128 KiB
    short* H0hi = sH;
    short* H0lo = sH + 1 * ROWS_PER_BLK * HIDDEN;
    short* H1hi = sH + 2 * ROWS_PER_BLK * HIDDEN;
    short* H1lo = sH + 3 * ROWS_PER_BLK * HIDDEN;
    float* fl   = (float*)sH;                            // prologue alias [64][512]

    const int tid  = threadIdx.x;
    const int wave = tid >> 6, lane = tid & 63;
    const int lr = lane & 15, lg = lane >> 4;
    const int rowbase = blockIdx.x * ROWS_PER_BLK;

    const short *WpHi   = Whi + OFF_Wp,   *WpLo   = Wlo + OFF_Wp;
    const short *Wih0Hi = Whi + OFF_Wih0, *Wih0Lo = Wlo + OFF_Wih0;
    const short *Whh0Hi = Whi + OFF_Whh0, *Whh0Lo = Wlo + OFF_Whh0;
    const short *Wih1Hi = Whi + OFF_Wih1, *Wih1Lo = Wlo + OFF_Wih1;
    const short *Whh1Hi = Whi + OFF_Whh1, *Whh1Lo = Wlo + OFF_Whh1;
    const short *WoHi   = Whi + OFF_Wo,   *WoLo   = Wlo + OFF_Wo;

    // ---- per-lane bias registers (fixed across steps) ----
    float br0[2], bz0[2], bi0[2], bh0[2];
    float br1[2], bz1[2], bi1[2], bh1[2];
#pragma unroll
    for (int p = 0; p < 2; p++) {
        int c = wave * 32 + p * 16 + lr;
        br0[p] = bih0[c] + bhh0[c];
        bz0[p] = bih0[HIDDEN + c] + bhh0[HIDDEN + c];
        bi0[p] = bih0[2 * HIDDEN + c];
        bh0[p] = bhh0[2 * HIDDEN + c];
        br1[p] = bih1[c] + bhh1[c];
        bz1[p] = bih1[HIDDEN + c] + bhh1[HIDDEN + c];
        bi1[p] = bih1[2 * HIDDEN + c];
        bh1[p] = bhh1[2 * HIDDEN + c];
    }
    const int scol = wave * 16 + lr;
    const float bo_v = bo[scol];
    float bpv[2];
    bpv[0] = bp[wave * 32 + lr];
    bpv[1] = bp[wave * 32 + 16 + lr];

    // ===== prologue: h_init = emb @ Wp^T + bp (emb fp32 across all 128KB) =====
    for (int idx = tid; idx < ROWS_PER_BLK * EMBED; idx += THREADS) {
        int r = idx >> 9, c = idx & (EMBED - 1);
        fl[fswz(r, c)] = emb[(size_t)(rowbase + r) * EMBED + c];
    }
    __syncthreads();
    f32x4 hacc[2][4];
    {
        f32x4 zz = {0.f, 0.f, 0.f, 0.f};
#pragma unroll
        for (int nt = 0; nt < 2; nt++)
#pragma unroll
            for (int mt = 0; mt < 4; mt++) hacc[nt][mt] = zz;
    }
#pragma unroll 2
    for (int kc = 0; kc < EMBED / 32; kc++) {
        const int k0 = kc * 32 + lg * 8;
        s16x8 ahi[4], alo[4];
#pragma unroll
        for (int mt = 0; mt < 4; mt++)
            lds_frag_f32(fl, mt * 16 + lr, k0, ahi[mt], alo[mt]);
#pragma unroll
        for (int nt = 0; nt < 2; nt++)
            catblock<EMBED>(hacc[nt], ahi, alo, WpHi, WpLo, wave * 32 + nt * 16 + lr, k0);
    }
    __syncthreads();   // emb reads done before overwriting LDS with H planes
#pragma unroll
    for (int nt = 0; nt < 2; nt++)
#pragma unroll
        for (int mt = 0; mt < 4; mt++)
#pragma unroll
            for (int j = 0; j < 4; j++) {
                int row = mt * 16 + lg * 4 + j;
                int col = wave * 32 + nt * 16 + lr;
                float v = hacc[nt][mt][j] + bpv[nt];
                short hi = f2bf(v);
                short lo = f2bf(v - bf2f(hi));
                H0hi[sidx(row, col)] = hi;  H0lo[sidx(row, col)] = lo;
                H1hi[sidx(row, col)] = hi;  H1lo[sidx(row, col)] = lo;
            }
    __syncthreads();

    // ===== 32 recurrent steps =====
#pragma unroll 1
    for (int t = 0; t < HORIZON; t++) {
        float hn0[2][4][4];
        gru_layer<STATE, true>(Shi, Slo, H0hi, H0lo,
                               Wih0Hi, Wih0Lo, Whh0Hi, Whh0Lo,
                               br0, bz0, bi0, bh0,
                               rowbase, wave, lr, lg, hn0);
        __syncthreads();                 // all reads of old H0 done
        write_h(H0hi, H0lo, hn0, wave, lr, lg);
        __syncthreads();                 // new H0 visible

        float hn1[2][4][4];
        gru_layer<HIDDEN, false>(H0hi, H0lo, H1hi, H1lo,
                                 Wih1Hi, Wih1Lo, Whh1Hi, Whh1Lo,
                                 br1, bz1, bi1, bh1,
                                 rowbase, wave, lr, lg, hn1);
        __syncthreads();                 // all reads of old H1 done
        write_h(H1hi, H1lo, hn1, wave, lr, lg);
        __syncthreads();                 // new H1 visible

        // ---- next_state = h1 @ Wo^T + bo ; emit out[:,t,:] and S planes ----
        f32x4 o[4];
        {
            f32x4 zz = {0.f, 0.f, 0.f, 0.f};
#pragma unroll
            for (int mt = 0; mt < 4; mt++) o[mt] = zz;
        }
#pragma unroll 2
        for (int kc = 0; kc < HIDDEN / 32; kc++) {
            const int k0 = kc * 32 + lg * 8;
            s16x8 ahi[4], alo[4];
#pragma unroll
            for (int mt = 0; mt < 4; mt++) {
                int off = sfrag(mt * 16 + lr, k0);
                ahi[mt] = *(const s16x8*)(H1hi + off);
                alo[mt] = *(const s16x8*)(H1lo + off);
            }
            catblock<HIDDEN>(o, ahi, alo, WoHi, WoLo, scol, k0);
        }
#pragma unroll
        for (int mt = 0; mt < 4; mt++)
#pragma unroll
            for (int j = 0; j < 4; j++) {
                int row   = mt * 16 + lg * 4 + j;
                size_t gr = (size_t)(rowbase + row);
                float v   = o[mt][j] + bo_v;
                out[gr * (size_t)(HORIZON * STATE) + (size_t)t * STATE + scol] = v;
                short hi = f2bf(v);
                short lo = f2bf(v - bf2f(hi));
                Shi[gr * STATE + scol] = hi;
                Slo[gr * STATE + scol] = lo;
            }
        __threadfence_block();   // S plane writes visible to next step's reads
        __syncthreads();
    }
}

extern "C" void kernel_launch(void* const* d_in, const int* in_sizes, int n_in,
                              void* d_out, int out_size, void* d_ws, size_t ws_size,
                              hipStream_t stream) {
    (void)in_sizes; (void)n_in; (void)out_size; (void)ws_size;
    const float* emb  = (const float*)d_in[0];
    const float* st0  = (const float*)d_in[1];
    const float* Wp   = (const float*)d_in[2];
    const float* bp   = (const float*)d_in[3];
    const float* Wih0 = (const float*)d_in[4];
    const float* Whh0 = (const float*)d_in[5];
    const float* bih0 = (const float*)d_in[6];
    const float* bhh0 = (const float*)d_in[7];
    const float* Wih1 = (const float*)d_in[8];
    const float* Whh1 = (const float*)d_in[9];
    const float* bih1 = (const float*)d_in[10];
    const float* bhh1 = (const float*)d_in[11];
    const float* Wo   = (const float*)d_in[12];
    const float* bo   = (const float*)d_in[13];
    float* out = (float*)d_out;

    // d_ws layout: [ Shi 4MB | Slo 4MB | Whi | Wlo ]  (bf16 planes)
    short* shi = (short*)d_ws;
    short* slo = shi + (size_t)BTOT * STATE;
    short* whi = slo + (size_t)BTOT * STATE;
    short* wlo = whi + N_WTOT;

    prep_split<<<(N_WTOT + 255) / 256, 256, 0, stream>>>(Wp, Wih0, Whh0, Wih1, Whh1, Wo, whi, wlo);
    prep_state<<<(BTOT * STATE + 255) / 256, 256, 0, stream>>>(st0, shi, slo);
    gru_main<<<BTOT / ROWS_PER_BLK, THREADS, 0, stream>>>(
        emb, bp, bih0, bhh0, bih1, bhh1, bo, whi, wlo, shi, slo, out);
}